// Round 1
// baseline (2579.756 us; speedup 1.0000x reference)
//
#include <hip/hip_runtime.h>
#include <math.h>

// Dims (fixed by the problem)
#define T_ 256
#define F_ 256
#define B_ 64      // C*N
#define H_ 8
#define HD_ 32
#define E_ 1024
#define D_ 262144  // T*F*C
#define N_ 16
#define M_ 16384   // B_*T_ tokens

typedef __attribute__((ext_vector_type(8))) short bf16x8;
typedef __attribute__((ext_vector_type(4))) float f32x4;

// ---------------------------------------------------------------- build h ---
__global__ __launch_bounds__(256) void build_h(const float* __restrict__ x,
                                               float* __restrict__ h) {
    int idx = blockIdx.x * 256 + threadIdx.x;   // < 64*256*256
    int f = idx & 255;
    int t = (idx >> 8) & 255;
    int b = idx >> 16;
    int c = b >> 4;
    int n = b & 15;
    h[idx] = x[((n * 256 + f) * 256 + t) * 4 + c] + (float)t * (1.0f / 255.0f);
}

// ---------------------------------------------------------------- attention ---
__global__ __launch_bounds__(256) void attn_kernel(const float* __restrict__ h,
                                                   const float* __restrict__ Wq,
                                                   const float* __restrict__ Wk,
                                                   const float* __restrict__ Wv,
                                                   float* __restrict__ o) {
    __shared__ float ks[256][32];
    __shared__ float vs[256][32];
    const int b = blockIdx.x >> 3;
    const int hh = blockIdx.x & 7;
    const int t = threadIdx.x;

    const float* zp = h + (b * 256 + t) * 256 + hh * 32;
    float z[32];
#pragma unroll
    for (int e4 = 0; e4 < 8; ++e4) {
        float4 tv = *(const float4*)(zp + e4 * 4);
        z[e4 * 4 + 0] = tv.x; z[e4 * 4 + 1] = tv.y;
        z[e4 * 4 + 2] = tv.z; z[e4 * 4 + 3] = tv.w;
    }

    float q[32];
#pragma unroll
    for (int dg = 0; dg < 8; ++dg) {
        float4 k4, v4;
#pragma unroll
        for (int di = 0; di < 4; ++di) {
            const int d = dg * 4 + di;
            const float* wq = Wq + d * 32;
            const float* wk = Wk + d * 32;
            const float* wv = Wv + d * 32;
            float qd = 0.f, kd = 0.f, vd = 0.f;
#pragma unroll
            for (int e = 0; e < 32; ++e) {
                qd += z[e] * wq[e];
                kd += z[e] * wk[e];
                vd += z[e] * wv[e];
            }
            q[d] = qd * 0.0625f;      // scale = 1/sqrt(F=256)
            (&k4.x)[di] = kd;
            (&v4.x)[di] = vd;
        }
        *(float4*)&ks[t][dg * 4] = k4;
        *(float4*)&vs[t][dg * 4] = v4;
    }
    __syncthreads();

    float m = -1e30f, lsum = 0.f;
    float oacc[32];
#pragma unroll
    for (int e = 0; e < 32; ++e) oacc[e] = 0.f;

    for (int j = 0; j < 256; ++j) {
        const float4* kp = (const float4*)&ks[j][0];
        float s = 0.f;
#pragma unroll
        for (int e4 = 0; e4 < 8; ++e4) {
            float4 kv = kp[e4];
            s += q[e4 * 4 + 0] * kv.x + q[e4 * 4 + 1] * kv.y +
                 q[e4 * 4 + 2] * kv.z + q[e4 * 4 + 3] * kv.w;
        }
        float mn = fmaxf(m, s);
        float alpha = __expf(m - mn);
        float p = __expf(s - mn);
        lsum = lsum * alpha + p;
        const float4* vp = (const float4*)&vs[j][0];
#pragma unroll
        for (int e4 = 0; e4 < 8; ++e4) {
            float4 vv = vp[e4];
            oacc[e4 * 4 + 0] = oacc[e4 * 4 + 0] * alpha + p * vv.x;
            oacc[e4 * 4 + 1] = oacc[e4 * 4 + 1] * alpha + p * vv.y;
            oacc[e4 * 4 + 2] = oacc[e4 * 4 + 2] * alpha + p * vv.z;
            oacc[e4 * 4 + 3] = oacc[e4 * 4 + 3] * alpha + p * vv.w;
        }
        m = mn;
    }
    const float inv = 1.0f / lsum;
    float* op = o + (b * 256 + t) * 256 + hh * 32;
#pragma unroll
    for (int e4 = 0; e4 < 8; ++e4) {
        float4 ov;
        ov.x = oacc[e4 * 4 + 0] * inv; ov.y = oacc[e4 * 4 + 1] * inv;
        ov.z = oacc[e4 * 4 + 2] * inv; ov.w = oacc[e4 * 4 + 3] * inv;
        *(float4*)(op + e4 * 4) = ov;
    }
}

// --------------------------------------------- split-bf16 MFMA GEMM -----------
// C[M,Nn] = A[M,K] @ W[Nn,K]^T + bias (+relu), fp32 in/out.
// Each fp32 value split as v = hi + lo (bf16 each, truncate-split); product via
// 3 MFMAs (lo*hi, hi*lo, hi*hi) -> ~2^-16 relative error.
// 128x128 tile, 4 waves, each wave 4x4 tiles of 16x16x32 MFMA. K-chunk 32.
#define LDST 40   // LDS row stride in shorts (padded: 80B rows, 16B-aligned)

struct GemmLds {
    short Ahi[128][LDST];
    short Alo[128][LDST];
    short Whi[128][LDST];
    short Wlo[128][LDST];
};

__device__ inline void split2(float a0, float a1, unsigned& hi, unsigned& lo) {
    unsigned u0 = __float_as_uint(a0), u1 = __float_as_uint(a1);
    hi = __builtin_amdgcn_perm(u1, u0, 0x07060302);
    float r0 = a0 - __uint_as_float(u0 & 0xffff0000u);
    float r1 = a1 - __uint_as_float(u1 & 0xffff0000u);
    lo = __builtin_amdgcn_perm(__float_as_uint(r1), __float_as_uint(r0), 0x07060302);
}

__global__ __launch_bounds__(256, 2) void gemm_mfma(const float* __restrict__ A,
                                                    const float* __restrict__ W,
                                                    const float* __restrict__ bias,
                                                    float* __restrict__ C,
                                                    int M, int Nn, int K, int doRelu) {
    __shared__ GemmLds lds;
    const int tid = threadIdx.x;
    const int row0 = blockIdx.y * 128, col0 = blockIdx.x * 128;
    const int wave = tid >> 6, lane = tid & 63;
    const int wr = wave >> 1, wc = wave & 1;      // wave origin (wr*64, wc*64)
    const int lrow = tid >> 3;                     // 0..31
    const int lcol = (tid & 7) * 4;                // 0,4,...,28

    f32x4 acc[4][4];
#pragma unroll
    for (int i = 0; i < 4; ++i)
#pragma unroll
        for (int j = 0; j < 4; ++j) acc[i][j] = (f32x4){0.f, 0.f, 0.f, 0.f};

    float4 abuf[4], wbuf[4];
#pragma unroll
    for (int jj = 0; jj < 4; ++jj) {
        abuf[jj] = *(const float4*)&A[(size_t)(row0 + jj * 32 + lrow) * K + lcol];
        wbuf[jj] = *(const float4*)&W[(size_t)(col0 + jj * 32 + lrow) * K + lcol];
    }

    for (int k0 = 0; k0 < K; k0 += 32) {
        // convert + stage to LDS
#pragma unroll
        for (int jj = 0; jj < 4; ++jj) {
            const int row = jj * 32 + lrow;
            unsigned h01, l01, h23, l23;
            split2(abuf[jj].x, abuf[jj].y, h01, l01);
            split2(abuf[jj].z, abuf[jj].w, h23, l23);
            *(uint2*)&lds.Ahi[row][lcol] = make_uint2(h01, h23);
            *(uint2*)&lds.Alo[row][lcol] = make_uint2(l01, l23);
            split2(wbuf[jj].x, wbuf[jj].y, h01, l01);
            split2(wbuf[jj].z, wbuf[jj].w, h23, l23);
            *(uint2*)&lds.Whi[row][lcol] = make_uint2(h01, h23);
            *(uint2*)&lds.Wlo[row][lcol] = make_uint2(l01, l23);
        }
        __syncthreads();

        // prefetch next chunk while MFMAs run
        if (k0 + 32 < K) {
#pragma unroll
            for (int jj = 0; jj < 4; ++jj) {
                abuf[jj] = *(const float4*)&A[(size_t)(row0 + jj * 32 + lrow) * K + k0 + 32 + lcol];
                wbuf[jj] = *(const float4*)&W[(size_t)(col0 + jj * 32 + lrow) * K + k0 + 32 + lcol];
            }
        }

        const int fr = lane & 15, koff = (lane >> 4) * 8;
        bf16x8 ahi[4], alo[4], whi[4], wlo[4];
#pragma unroll
        for (int i = 0; i < 4; ++i) {
            ahi[i] = *(const bf16x8*)&lds.Ahi[wr * 64 + i * 16 + fr][koff];
            alo[i] = *(const bf16x8*)&lds.Alo[wr * 64 + i * 16 + fr][koff];
        }
#pragma unroll
        for (int j = 0; j < 4; ++j) {
            whi[j] = *(const bf16x8*)&lds.Whi[wc * 64 + j * 16 + fr][koff];
            wlo[j] = *(const bf16x8*)&lds.Wlo[wc * 64 + j * 16 + fr][koff];
        }
#pragma unroll
        for (int i = 0; i < 4; ++i)
#pragma unroll
            for (int j = 0; j < 4; ++j) {
                acc[i][j] = __builtin_amdgcn_mfma_f32_16x16x32_bf16(alo[i], whi[j], acc[i][j], 0, 0, 0);
                acc[i][j] = __builtin_amdgcn_mfma_f32_16x16x32_bf16(ahi[i], wlo[j], acc[i][j], 0, 0, 0);
                acc[i][j] = __builtin_amdgcn_mfma_f32_16x16x32_bf16(ahi[i], whi[j], acc[i][j], 0, 0, 0);
            }
        __syncthreads();
    }

    // epilogue: C/D layout col=lane&15, row=(lane>>4)*4+reg  [m89/m91]
    const int fr = lane & 15, rg = (lane >> 4) * 4;
#pragma unroll
    for (int j = 0; j < 4; ++j) {
        const int col = col0 + wc * 64 + j * 16 + fr;
        const float bv = bias[col];
#pragma unroll
        for (int i = 0; i < 4; ++i) {
#pragma unroll
            for (int r = 0; r < 4; ++r) {
                const int row = row0 + wr * 64 + i * 16 + rg + r;
                float v = acc[i][j][r] + bv;
                if (doRelu) v = fmaxf(v, 0.f);
                C[(size_t)row * Nn + col] = v;
            }
        }
    }
}

// ------------------------------------------------------ residual + layernorm ---
__global__ __launch_bounds__(256) void ln_residual(const float* __restrict__ A,
                                                   const float* __restrict__ R,
                                                   const float* __restrict__ g,
                                                   const float* __restrict__ b,
                                                   float* __restrict__ O) {
    const int row = blockIdx.x;
    const int tid = threadIdx.x;
    float v = A[row * 256 + tid] + R[row * 256 + tid];
    float s = v, sq = v * v;
#pragma unroll
    for (int off = 32; off > 0; off >>= 1) {
        s += __shfl_down(s, off, 64);
        sq += __shfl_down(sq, off, 64);
    }
    __shared__ float ss[4], ssq[4];
    const int wave = tid >> 6, lane = tid & 63;
    if (lane == 0) { ss[wave] = s; ssq[wave] = sq; }
    __syncthreads();
    float S = ss[0] + ss[1] + ss[2] + ss[3];
    float SQ = ssq[0] + ssq[1] + ssq[2] + ssq[3];
    float mean = S * (1.0f / 256.0f);
    float var = SQ * (1.0f / 256.0f) - mean * mean;
    float inv = rsqrtf(var + 1e-5f);
    O[row * 256 + tid] = (v - mean) * inv * g[tid] + b[tid];
}

// ---------------------------------------------------------------- head GEMM ---
// z[512,16] = W[512,D] @ flat[16,D]^T, flat[n, tf*4+c] = h[c][n][tf].
// Grid 512 = jt(2 heads, 256 j each) x kc(256 slices of 1024 d = 256 tf x 4 c).
// Block: stage h slice (64 KB) to LDS once; 256 threads = 64 j-groups x 4 c-lanes;
// each thread: 4 j x 16 n accumulators over 256 tf. Weight stream = 536 MB read
// exactly once (the compulsory traffic); h re-read factor drops 128x -> 2x.
__global__ __launch_bounds__(256) void head_gemm(const float* __restrict__ h,
                                                 const float* __restrict__ eW1,
                                                 const float* __restrict__ aW1,
                                                 float* __restrict__ zraw) {
    __shared__ float hs[256][64];   // [tf_local][c*16 + n]
    const int tid = threadIdx.x;
    const int jt = blockIdx.x >> 8;        // 0 = elev head, 1 = azim head
    const int kc = blockIdx.x & 255;       // k-slice
    const int tf0 = kc * 256;

    // ---- stage: wave w loads 64 contiguous tf for its (c,n) column ----
    {
        const int w = tid >> 6;            // wave id 0..3 -> tf sub-range
        const int cn = tid & 63;           // c*16 + n
        const int c = cn >> 4, n = cn & 15;
        const float* hp = h + c * 1048576 + n * 65536 + tf0 + w * 64;
#pragma unroll
        for (int k4 = 0; k4 < 16; ++k4) {
            float4 hv = *(const float4*)(hp + k4 * 4);
            hs[w * 64 + k4 * 4 + 0][cn] = hv.x;
            hs[w * 64 + k4 * 4 + 1][cn] = hv.y;
            hs[w * 64 + k4 * 4 + 2][cn] = hv.z;
            hs[w * 64 + k4 * 4 + 3][cn] = hv.w;
        }
    }
    __syncthreads();

    // ---- compute: thread (jg, c); j = jt*256 + jg*4 + jj ----
    const int jg = tid >> 2;
    const int c = tid & 3;
    const float* Wp = (jt ? aW1 : eW1) + (size_t)(jg * 4) * D_ + kc * 1024 + c;

    f32x4 acc[4][4];   // [jj][n4]
#pragma unroll
    for (int jj = 0; jj < 4; ++jj)
#pragma unroll
        for (int n4 = 0; n4 < 4; ++n4) acc[jj][n4] = (f32x4){0.f, 0.f, 0.f, 0.f};

#pragma unroll 4
    for (int i = 0; i < 256; ++i) {
        const float w0 = Wp[i * 4];
        const float w1 = Wp[i * 4 + D_];
        const float w2 = Wp[i * 4 + 2 * D_];
        const float w3 = Wp[i * 4 + 3 * D_];
        const f32x4* hv = (const f32x4*)&hs[i][c * 16];
        const f32x4 h0 = hv[0], h1 = hv[1], h2 = hv[2], h3 = hv[3];
        acc[0][0] += w0 * h0; acc[0][1] += w0 * h1; acc[0][2] += w0 * h2; acc[0][3] += w0 * h3;
        acc[1][0] += w1 * h0; acc[1][1] += w1 * h1; acc[1][2] += w1 * h2; acc[1][3] += w1 * h3;
        acc[2][0] += w2 * h0; acc[2][1] += w2 * h1; acc[2][2] += w2 * h2; acc[2][3] += w2 * h3;
        acc[3][0] += w3 * h0; acc[3][1] += w3 * h1; acc[3][2] += w3 * h2; acc[3][3] += w3 * h3;
    }

    // ---- reduce over the 4 c-lanes, then one atomicAdd per (j, n) ----
#pragma unroll
    for (int jj = 0; jj < 4; ++jj)
#pragma unroll
        for (int n4 = 0; n4 < 4; ++n4)
#pragma unroll
            for (int q = 0; q < 4; ++q) {
                float v = acc[jj][n4][q];
                v += __shfl_xor(v, 1, 64);
                v += __shfl_xor(v, 2, 64);
                acc[jj][n4][q] = v;
            }
    if (c == 0) {
        float* zp = zraw + jt * 4096 + jg * 4;
#pragma unroll
        for (int jj = 0; jj < 4; ++jj)
#pragma unroll
            for (int n4 = 0; n4 < 4; ++n4)
#pragma unroll
                for (int q = 0; q < 4; ++q)
                    atomicAdd(&zp[(n4 * 4 + q) * 256 + jj], acc[jj][n4][q]);
    }
}

__global__ __launch_bounds__(256) void zero_kernel(float* __restrict__ p) {
    p[blockIdx.x * 256 + threadIdx.x] = 0.f;
}

// ---------------------------------------------------------------- head MLP ---
__global__ __launch_bounds__(256) void mlp_head(const float* __restrict__ zr,
                                                const float* __restrict__ b1,
                                                const float* __restrict__ g,
                                                const float* __restrict__ bt,
                                                const float* __restrict__ W2,
                                                const float* __restrict__ b2,
                                                const float* __restrict__ W3,
                                                const float* __restrict__ b3,
                                                const float* __restrict__ W4,
                                                float* __restrict__ out,
                                                float lo, float hi, int coff) {
    __shared__ float za[256], zb[256];
    const int n = blockIdx.x, j = threadIdx.x;
    float z = zr[n * 256 + j] + b1[j];
    z = z * 0.99999500003749969f * g[j] + bt[j];   // 1/sqrt(1+1e-5)
    za[j] = fmaxf(z, 0.f);
    __syncthreads();
    float a = b2[j];
    for (int e = 0; e < 256; ++e) a += za[e] * W2[j * 256 + e];
    zb[j] = fmaxf(a, 0.f);
    __syncthreads();
    a = b3[j];
    for (int e = 0; e < 256; ++e) a += zb[e] * W3[j * 256 + e];
    za[j] = fmaxf(a, 0.f);
    __syncthreads();
    if (j < 2) {
        float v = 0.f;
        for (int e = 0; e < 256; ++e) v += za[e] * W4[j * 256 + e];
        v = fminf(fmaxf(v, lo), hi);
        out[n * 4 + 2 * j + coff] = v;
    }
}

// ---------------------------------------------------------------- launcher ---
extern "C" void kernel_launch(void* const* d_in, const int* in_sizes, int n_in,
                              void* d_out, int out_size, void* d_ws, size_t ws_size,
                              hipStream_t stream) {
    const float* x     = (const float*)d_in[0];
    const float* Wq    = (const float*)d_in[1];
    const float* Wk    = (const float*)d_in[2];
    const float* Wv    = (const float*)d_in[3];
    const float* Wo    = (const float*)d_in[4];
    const float* bo    = (const float*)d_in[5];
    const float* ln1g  = (const float*)d_in[6];
    const float* ln1b  = (const float*)d_in[7];
    const float* ln2g  = (const float*)d_in[8];
    const float* ln2b  = (const float*)d_in[9];
    const float* ffW1  = (const float*)d_in[10];
    const float* ffb1  = (const float*)d_in[11];
    const float* ffW2  = (const float*)d_in[12];
    const float* ffb2  = (const float*)d_in[13];
    const float* eW1   = (const float*)d_in[14];
    const float* eb1   = (const float*)d_in[15];
    const float* eg    = (const float*)d_in[16];
    const float* ebt   = (const float*)d_in[17];
    const float* eW2   = (const float*)d_in[18];
    const float* eb2   = (const float*)d_in[19];
    const float* eW3   = (const float*)d_in[20];
    const float* eb3   = (const float*)d_in[21];
    const float* eW4   = (const float*)d_in[22];
    const float* aW1   = (const float*)d_in[23];
    const float* ab1   = (const float*)d_in[24];
    const float* ag    = (const float*)d_in[25];
    const float* abt   = (const float*)d_in[26];
    const float* aW2   = (const float*)d_in[27];
    const float* ab2   = (const float*)d_in[28];
    const float* aW3   = (const float*)d_in[29];
    const float* ab3   = (const float*)d_in[30];
    const float* aW4   = (const float*)d_in[31];
    float* out = (float*)d_out;

    float* ws   = (float*)d_ws;
    float* h    = ws;                    // 4 Mi floats
    float* ao   = ws + 4194304;
    float* tmp  = ws + 8388608;
    float* x1   = ws + 12582912;
    float* ff1  = ws + 16777216;         // 16 Mi floats
    float* zraw = ws + 33554432;         // 8192 floats

    build_h<<<16384, 256, 0, stream>>>(x, h);

    for (int l = 0; l < 6; ++l) {
        attn_kernel<<<512, 256, 0, stream>>>(h, Wq + l * 1024, Wk + l * 1024,
                                             Wv + l * 1024, ao);
        gemm_mfma<<<dim3(2, 128), 256, 0, stream>>>(ao, Wo + l * 65536, bo + l * 256,
                                                    tmp, M_, 256, 256, 0);
        ln_residual<<<16384, 256, 0, stream>>>(tmp, h, ln1g + l * 256, ln1b + l * 256, x1);
        gemm_mfma<<<dim3(8, 128), 256, 0, stream>>>(x1, ffW1 + l * 262144, ffb1 + l * 1024,
                                                    ff1, M_, 1024, 256, 1);
        gemm_mfma<<<dim3(2, 128), 256, 0, stream>>>(ff1, ffW2 + l * 262144, ffb2 + l * 256,
                                                    tmp, M_, 256, 1024, 0);
        ln_residual<<<16384, 256, 0, stream>>>(tmp, x1, ln2g + l * 256, ln2b + l * 256, h);
    }

    zero_kernel<<<32, 256, 0, stream>>>(zraw);
    head_gemm<<<512, 256, 0, stream>>>(h, eW1, aW1, zraw);

    const float pi = 3.14159265358979323846f;
    mlp_head<<<16, 256, 0, stream>>>(zraw, eb1, eg, ebt, eW2, eb2, eW3, eb3, eW4,
                                     out, -pi / 4.f, pi / 2.f, 0);
    mlp_head<<<16, 256, 0, stream>>>(zraw + 4096, ab1, ag, abt, aW2, ab2, aW3, ab3, aW4,
                                     out, 0.f, 2.f * pi, 1);
}

// Round 2
// 2492.535 us; speedup vs baseline: 1.0350x; 1.0350x over previous
//
#include <hip/hip_runtime.h>
#include <math.h>

// Dims (fixed by the problem)
#define T_ 256
#define F_ 256
#define B_ 64      // C*N
#define H_ 8
#define HD_ 32
#define E_ 1024
#define D_ 262144  // T*F*C
#define N_ 16
#define M_ 16384   // B_*T_ tokens

typedef __attribute__((ext_vector_type(8))) short bf16x8;
typedef __attribute__((ext_vector_type(4))) float f32x4;
typedef unsigned short u16;

// ---------------------------------------------------------------- build h ---
__global__ __launch_bounds__(256) void build_h(const float* __restrict__ x,
                                               float* __restrict__ h) {
    int idx = blockIdx.x * 256 + threadIdx.x;   // < 64*256*256
    int f = idx & 255;
    int t = (idx >> 8) & 255;
    int b = idx >> 16;
    int c = b >> 4;
    int n = b & 15;
    h[idx] = x[((n * 256 + f) * 256 + t) * 4 + c] + (float)t * (1.0f / 255.0f);
}

// ---------------------------------------------------------------- attention ---
__global__ __launch_bounds__(256) void attn_kernel(const float* __restrict__ h,
                                                   const float* __restrict__ Wq,
                                                   const float* __restrict__ Wk,
                                                   const float* __restrict__ Wv,
                                                   float* __restrict__ o) {
    __shared__ float ks[256][32];
    __shared__ float vs[256][32];
    const int b = blockIdx.x >> 3;
    const int hh = blockIdx.x & 7;
    const int t = threadIdx.x;

    const float* zp = h + (b * 256 + t) * 256 + hh * 32;
    float z[32];
#pragma unroll
    for (int e4 = 0; e4 < 8; ++e4) {
        float4 tv = *(const float4*)(zp + e4 * 4);
        z[e4 * 4 + 0] = tv.x; z[e4 * 4 + 1] = tv.y;
        z[e4 * 4 + 2] = tv.z; z[e4 * 4 + 3] = tv.w;
    }

    float q[32];
#pragma unroll
    for (int dg = 0; dg < 8; ++dg) {
        float4 k4, v4;
#pragma unroll
        for (int di = 0; di < 4; ++di) {
            const int d = dg * 4 + di;
            const float* wq = Wq + d * 32;
            const float* wk = Wk + d * 32;
            const float* wv = Wv + d * 32;
            float qd = 0.f, kd = 0.f, vd = 0.f;
#pragma unroll
            for (int e = 0; e < 32; ++e) {
                qd += z[e] * wq[e];
                kd += z[e] * wk[e];
                vd += z[e] * wv[e];
            }
            q[d] = qd * 0.0625f;      // scale = 1/sqrt(F=256)
            (&k4.x)[di] = kd;
            (&v4.x)[di] = vd;
        }
        *(float4*)&ks[t][dg * 4] = k4;
        *(float4*)&vs[t][dg * 4] = v4;
    }
    __syncthreads();

    float m = -1e30f, lsum = 0.f;
    float oacc[32];
#pragma unroll
    for (int e = 0; e < 32; ++e) oacc[e] = 0.f;

    for (int j = 0; j < 256; ++j) {
        const float4* kp = (const float4*)&ks[j][0];
        float s = 0.f;
#pragma unroll
        for (int e4 = 0; e4 < 8; ++e4) {
            float4 kv = kp[e4];
            s += q[e4 * 4 + 0] * kv.x + q[e4 * 4 + 1] * kv.y +
                 q[e4 * 4 + 2] * kv.z + q[e4 * 4 + 3] * kv.w;
        }
        float mn = fmaxf(m, s);
        float alpha = __expf(m - mn);
        float p = __expf(s - mn);
        lsum = lsum * alpha + p;
        const float4* vp = (const float4*)&vs[j][0];
#pragma unroll
        for (int e4 = 0; e4 < 8; ++e4) {
            float4 vv = vp[e4];
            oacc[e4 * 4 + 0] = oacc[e4 * 4 + 0] * alpha + p * vv.x;
            oacc[e4 * 4 + 1] = oacc[e4 * 4 + 1] * alpha + p * vv.y;
            oacc[e4 * 4 + 2] = oacc[e4 * 4 + 2] * alpha + p * vv.z;
            oacc[e4 * 4 + 3] = oacc[e4 * 4 + 3] * alpha + p * vv.w;
        }
        m = mn;
    }
    const float inv = 1.0f / lsum;
    float* op = o + (b * 256 + t) * 256 + hh * 32;
#pragma unroll
    for (int e4 = 0; e4 < 8; ++e4) {
        float4 ov;
        ov.x = oacc[e4 * 4 + 0] * inv; ov.y = oacc[e4 * 4 + 1] * inv;
        ov.z = oacc[e4 * 4 + 2] * inv; ov.w = oacc[e4 * 4 + 3] * inv;
        *(float4*)(op + e4 * 4) = ov;
    }
}

// --------------------------------------------- split-bf16 MFMA GEMM -----------
// C[M,Nn] = A[M,K] @ W[Nn,K]^T + bias (+relu), fp32 in/out.
// Each fp32 value split as v = hi + lo (bf16 each, truncate-split); product via
// 3 MFMAs (lo*hi, hi*lo, hi*hi) -> ~2^-16 relative error.
// 128x128 tile, 4 waves, each wave 4x4 tiles of 16x16x32 MFMA. K-chunk 32.
#define LDST 40   // LDS row stride in shorts (padded: 80B rows, 16B-aligned)

struct GemmLds {
    short Ahi[128][LDST];
    short Alo[128][LDST];
    short Whi[128][LDST];
    short Wlo[128][LDST];
};

__device__ inline void split2(float a0, float a1, unsigned& hi, unsigned& lo) {
    unsigned u0 = __float_as_uint(a0), u1 = __float_as_uint(a1);
    hi = __builtin_amdgcn_perm(u1, u0, 0x07060302);
    float r0 = a0 - __uint_as_float(u0 & 0xffff0000u);
    float r1 = a1 - __uint_as_float(u1 & 0xffff0000u);
    lo = __builtin_amdgcn_perm(__float_as_uint(r1), __float_as_uint(r0), 0x07060302);
}

__global__ __launch_bounds__(256, 2) void gemm_mfma(const float* __restrict__ A,
                                                    const float* __restrict__ W,
                                                    const float* __restrict__ bias,
                                                    float* __restrict__ C,
                                                    int M, int Nn, int K, int doRelu) {
    __shared__ GemmLds lds;
    const int tid = threadIdx.x;
    const int row0 = blockIdx.y * 128, col0 = blockIdx.x * 128;
    const int wave = tid >> 6, lane = tid & 63;
    const int wr = wave >> 1, wc = wave & 1;      // wave origin (wr*64, wc*64)
    const int lrow = tid >> 3;                     // 0..31
    const int lcol = (tid & 7) * 4;                // 0,4,...,28

    f32x4 acc[4][4];
#pragma unroll
    for (int i = 0; i < 4; ++i)
#pragma unroll
        for (int j = 0; j < 4; ++j) acc[i][j] = (f32x4){0.f, 0.f, 0.f, 0.f};

    float4 abuf[4], wbuf[4];
#pragma unroll
    for (int jj = 0; jj < 4; ++jj) {
        abuf[jj] = *(const float4*)&A[(size_t)(row0 + jj * 32 + lrow) * K + lcol];
        wbuf[jj] = *(const float4*)&W[(size_t)(col0 + jj * 32 + lrow) * K + lcol];
    }

    for (int k0 = 0; k0 < K; k0 += 32) {
        // convert + stage to LDS
#pragma unroll
        for (int jj = 0; jj < 4; ++jj) {
            const int row = jj * 32 + lrow;
            unsigned h01, l01, h23, l23;
            split2(abuf[jj].x, abuf[jj].y, h01, l01);
            split2(abuf[jj].z, abuf[jj].w, h23, l23);
            *(uint2*)&lds.Ahi[row][lcol] = make_uint2(h01, h23);
            *(uint2*)&lds.Alo[row][lcol] = make_uint2(l01, l23);
            split2(wbuf[jj].x, wbuf[jj].y, h01, l01);
            split2(wbuf[jj].z, wbuf[jj].w, h23, l23);
            *(uint2*)&lds.Whi[row][lcol] = make_uint2(h01, h23);
            *(uint2*)&lds.Wlo[row][lcol] = make_uint2(l01, l23);
        }
        __syncthreads();

        // prefetch next chunk while MFMAs run
        if (k0 + 32 < K) {
#pragma unroll
            for (int jj = 0; jj < 4; ++jj) {
                abuf[jj] = *(const float4*)&A[(size_t)(row0 + jj * 32 + lrow) * K + k0 + 32 + lcol];
                wbuf[jj] = *(const float4*)&W[(size_t)(col0 + jj * 32 + lrow) * K + k0 + 32 + lcol];
            }
        }

        const int fr = lane & 15, koff = (lane >> 4) * 8;
        bf16x8 ahi[4], alo[4], whi[4], wlo[4];
#pragma unroll
        for (int i = 0; i < 4; ++i) {
            ahi[i] = *(const bf16x8*)&lds.Ahi[wr * 64 + i * 16 + fr][koff];
            alo[i] = *(const bf16x8*)&lds.Alo[wr * 64 + i * 16 + fr][koff];
        }
#pragma unroll
        for (int j = 0; j < 4; ++j) {
            whi[j] = *(const bf16x8*)&lds.Whi[wc * 64 + j * 16 + fr][koff];
            wlo[j] = *(const bf16x8*)&lds.Wlo[wc * 64 + j * 16 + fr][koff];
        }
#pragma unroll
        for (int i = 0; i < 4; ++i)
#pragma unroll
            for (int j = 0; j < 4; ++j) {
                acc[i][j] = __builtin_amdgcn_mfma_f32_16x16x32_bf16(alo[i], whi[j], acc[i][j], 0, 0, 0);
                acc[i][j] = __builtin_amdgcn_mfma_f32_16x16x32_bf16(ahi[i], wlo[j], acc[i][j], 0, 0, 0);
                acc[i][j] = __builtin_amdgcn_mfma_f32_16x16x32_bf16(ahi[i], whi[j], acc[i][j], 0, 0, 0);
            }
        __syncthreads();
    }

    // epilogue: C/D layout col=lane&15, row=(lane>>4)*4+reg  [m89/m91]
    const int fr = lane & 15, rg = (lane >> 4) * 4;
#pragma unroll
    for (int j = 0; j < 4; ++j) {
        const int col = col0 + wc * 64 + j * 16 + fr;
        const float bv = bias[col];
#pragma unroll
        for (int i = 0; i < 4; ++i) {
#pragma unroll
            for (int r = 0; r < 4; ++r) {
                const int row = row0 + wr * 64 + i * 16 + rg + r;
                float v = acc[i][j][r] + bv;
                if (doRelu) v = fmaxf(v, 0.f);
                C[(size_t)row * Nn + col] = v;
            }
        }
    }
}

// ------------------------------------------------------ residual + layernorm ---
__global__ __launch_bounds__(256) void ln_residual(const float* __restrict__ A,
                                                   const float* __restrict__ R,
                                                   const float* __restrict__ g,
                                                   const float* __restrict__ b,
                                                   float* __restrict__ O) {
    const int row = blockIdx.x;
    const int tid = threadIdx.x;
    float v = A[row * 256 + tid] + R[row * 256 + tid];
    float s = v, sq = v * v;
#pragma unroll
    for (int off = 32; off > 0; off >>= 1) {
        s += __shfl_down(s, off, 64);
        sq += __shfl_down(sq, off, 64);
    }
    __shared__ float ss[4], ssq[4];
    const int wave = tid >> 6, lane = tid & 63;
    if (lane == 0) { ss[wave] = s; ssq[wave] = sq; }
    __syncthreads();
    float S = ss[0] + ss[1] + ss[2] + ss[3];
    float SQ = ssq[0] + ssq[1] + ssq[2] + ssq[3];
    float mean = S * (1.0f / 256.0f);
    float var = SQ * (1.0f / 256.0f) - mean * mean;
    float inv = rsqrtf(var + 1e-5f);
    O[row * 256 + tid] = (v - mean) * inv * g[tid] + b[tid];
}

// ------------------------------------------------- flat -> bf16 hi/lo split ---
// Bhi/Blo[n][d] (bf16), d = tf*4 + c, flat[n,d] = h[(c*16+n)*65536 + tf].
__global__ __launch_bounds__(256) void bsplit_kernel(const float* __restrict__ h,
                                                     u16* __restrict__ Bhi,
                                                     u16* __restrict__ Blo) {
    const int idx = blockIdx.x * 256 + threadIdx.x;   // 16 n * 65536 tf
    const int n = idx >> 16;
    const int tf = idx & 65535;
    const float f0 = h[n * 65536 + tf];
    const float f1 = h[1048576 + n * 65536 + tf];
    const float f2 = h[2097152 + n * 65536 + tf];
    const float f3 = h[3145728 + n * 65536 + tf];
    unsigned h01, l01, h23, l23;
    split2(f0, f1, h01, l01);
    split2(f2, f3, h23, l23);
    *(uint2*)&Bhi[(size_t)n * D_ + tf * 4] = make_uint2(h01, h23);
    *(uint2*)&Blo[(size_t)n * D_ + tf * 4] = make_uint2(l01, l23);
}

// ---------------------------------------------------------------- head GEMM ---
// z[512,16] = W[512,D] @ flat[16,D]^T via split-bf16 MFMA (3-term, like gemm_mfma).
// Grid 1024 = 512 k-blocks (512 d each) x 2 heads. Block = 4 waves; wave w owns
// k-quarter (128 d) and all 16 j-tiles of 16 rows (A = W, split on the fly from
// dwordx4 streams; B = flat bf16 hi/lo staged in 32 KB LDS, XOR-swizzled 16B
// units -> conflict-free frag reads). Cross-wave LDS reduce, then atomics.
// VALU per 32B weights: ~24 (split2) vs 256 FMA-cycles scalar -> HBM-roofline.
struct HeadLds {
    union {
        struct { u16 bhi[16][512]; u16 blo[16][512]; } b;
        float red[2][4096];
    };
};

__global__ __launch_bounds__(256, 4) void head_gemm(const float* __restrict__ eW1,
                                                    const float* __restrict__ aW1,
                                                    const u16* __restrict__ Bhi,
                                                    const u16* __restrict__ Blo,
                                                    float* __restrict__ zraw) {
    __shared__ HeadLds lds;
    const int tid = threadIdx.x;
    const int head = blockIdx.x & 1;
    const int kb = blockIdx.x >> 1;
    const int K0 = kb * 512;               // d-offset of this block's window
    const int wv = tid >> 6, lane = tid & 63;
    const int fr = lane & 15;              // A row within j-tile == B row (n)
    const int kg = lane >> 4;              // k-group 0..3 (8 elems each)

    // ---- stage B window (16 n x 512 d, hi+lo) ; 16B unit u stored at u^(n&7) ----
    {
        const int u = lane;                // 0..63 16B-units per row
        for (int rr = 0; rr < 4; ++rr) {
            const int n = rr * 4 + wv;
            const int us = u ^ (n & 7);
            *(uint4*)&lds.b.bhi[n][us * 8] = *(const uint4*)&Bhi[(size_t)n * D_ + K0 + u * 8];
            *(uint4*)&lds.b.blo[n][us * 8] = *(const uint4*)&Blo[(size_t)n * D_ + K0 + u * 8];
        }
    }
    __syncthreads();

    f32x4 acc[16];
#pragma unroll
    for (int jt = 0; jt < 16; ++jt) acc[jt] = (f32x4){0.f, 0.f, 0.f, 0.f};

    const int kq = wv * 128;               // this wave's k-quarter
    const float* ap0 = (head ? aW1 : eW1) + (size_t)fr * D_ + K0 + kq + kg * 8;

    // 64 steps: jt = it>>2 (j-tile), ksl = it&3 (32-k step). Depth-2 A pipeline.
#define HG_ADDR(it) (ap0 + (size_t)((it) >> 2) * (16 * D_) + ((it) & 3) * 32)
    float4 c0 = *(const float4*)HG_ADDR(0);
    float4 c1 = *(const float4*)(HG_ADDR(0) + 4);
    float4 m0 = *(const float4*)HG_ADDR(1);
    float4 m1 = *(const float4*)(HG_ADDR(1) + 4);
#pragma unroll
    for (int it = 0; it < 64; ++it) {
        float4 n0, n1;
        if (it < 62) {
            n0 = *(const float4*)HG_ADDR(it + 2);
            n1 = *(const float4*)(HG_ADDR(it + 2) + 4);
        }
        // B fragment for this 32-k step (broadcast across j-tiles)
        const int u = (kq + (it & 3) * 32 + kg * 8) >> 3;
        const int us = u ^ (fr & 7);
        bf16x8 bh = *(const bf16x8*)&lds.b.bhi[fr][us * 8];
        bf16x8 bl = *(const bf16x8*)&lds.b.blo[fr][us * 8];
        // split A (8 fp32 -> bf16 hi/lo)
        unsigned h01, l01, h23, l23, h45, l45, h67, l67;
        split2(c0.x, c0.y, h01, l01);
        split2(c0.z, c0.w, h23, l23);
        split2(c1.x, c1.y, h45, l45);
        split2(c1.z, c1.w, h67, l67);
        union { bf16x8 v; unsigned u[4]; } ah, al;
        ah.u[0] = h01; ah.u[1] = h23; ah.u[2] = h45; ah.u[3] = h67;
        al.u[0] = l01; al.u[1] = l23; al.u[2] = l45; al.u[3] = l67;
        const int jt = it >> 2;
        acc[jt] = __builtin_amdgcn_mfma_f32_16x16x32_bf16(al.v, bh, acc[jt], 0, 0, 0);
        acc[jt] = __builtin_amdgcn_mfma_f32_16x16x32_bf16(ah.v, bl, acc[jt], 0, 0, 0);
        acc[jt] = __builtin_amdgcn_mfma_f32_16x16x32_bf16(ah.v, bh, acc[jt], 0, 0, 0);
        c0 = m0; c1 = m1; m0 = n0; m1 = n1;
    }
#undef HG_ADDR

    // ---- cross-wave reduce in LDS (reuse B region), then atomics from wave 0 ----
    // Lane's D-frag: col(n) = fr, rows = jt*16 + kg*4 + r. LDS unit = fr*4+kg.
    const int ru = (fr * 4 + kg) * 4;
    __syncthreads();
    if (wv >= 2) {
#pragma unroll
        for (int jt = 0; jt < 16; ++jt)
            *(f32x4*)&lds.red[wv - 2][jt * 256 + ru] = acc[jt];
    }
    __syncthreads();
    if (wv < 2) {
#pragma unroll
        for (int jt = 0; jt < 16; ++jt)
            acc[jt] += *(const f32x4*)&lds.red[wv][jt * 256 + ru];
    }
    __syncthreads();
    if (wv == 1) {
#pragma unroll
        for (int jt = 0; jt < 16; ++jt)
            *(f32x4*)&lds.red[0][jt * 256 + ru] = acc[jt];
    }
    __syncthreads();
    if (wv == 0) {
#pragma unroll
        for (int jt = 0; jt < 16; ++jt) {
            f32x4 v = acc[jt] + *(const f32x4*)&lds.red[0][jt * 256 + ru];
            float* zp = zraw + head * 4096 + fr * 256 + jt * 16 + kg * 4;
            atomicAdd(&zp[0], v[0]);
            atomicAdd(&zp[1], v[1]);
            atomicAdd(&zp[2], v[2]);
            atomicAdd(&zp[3], v[3]);
        }
    }
}

__global__ __launch_bounds__(256) void zero_kernel(float* __restrict__ p) {
    p[blockIdx.x * 256 + threadIdx.x] = 0.f;
}

// ---------------------------------------------------------------- head MLP ---
__global__ __launch_bounds__(256) void mlp_head(const float* __restrict__ zr,
                                                const float* __restrict__ b1,
                                                const float* __restrict__ g,
                                                const float* __restrict__ bt,
                                                const float* __restrict__ W2,
                                                const float* __restrict__ b2,
                                                const float* __restrict__ W3,
                                                const float* __restrict__ b3,
                                                const float* __restrict__ W4,
                                                float* __restrict__ out,
                                                float lo, float hi, int coff) {
    __shared__ float za[256], zb[256];
    const int n = blockIdx.x, j = threadIdx.x;
    float z = zr[n * 256 + j] + b1[j];
    z = z * 0.99999500003749969f * g[j] + bt[j];   // 1/sqrt(1+1e-5)
    za[j] = fmaxf(z, 0.f);
    __syncthreads();
    float a = b2[j];
    for (int e = 0; e < 256; ++e) a += za[e] * W2[j * 256 + e];
    zb[j] = fmaxf(a, 0.f);
    __syncthreads();
    a = b3[j];
    for (int e = 0; e < 256; ++e) a += zb[e] * W3[j * 256 + e];
    za[j] = fmaxf(a, 0.f);
    __syncthreads();
    if (j < 2) {
        float v = 0.f;
        for (int e = 0; e < 256; ++e) v += za[e] * W4[j * 256 + e];
        v = fminf(fmaxf(v, lo), hi);
        out[n * 4 + 2 * j + coff] = v;
    }
}

// ---------------------------------------------------------------- launcher ---
extern "C" void kernel_launch(void* const* d_in, const int* in_sizes, int n_in,
                              void* d_out, int out_size, void* d_ws, size_t ws_size,
                              hipStream_t stream) {
    const float* x     = (const float*)d_in[0];
    const float* Wq    = (const float*)d_in[1];
    const float* Wk    = (const float*)d_in[2];
    const float* Wv    = (const float*)d_in[3];
    const float* Wo    = (const float*)d_in[4];
    const float* bo    = (const float*)d_in[5];
    const float* ln1g  = (const float*)d_in[6];
    const float* ln1b  = (const float*)d_in[7];
    const float* ln2g  = (const float*)d_in[8];
    const float* ln2b  = (const float*)d_in[9];
    const float* ffW1  = (const float*)d_in[10];
    const float* ffb1  = (const float*)d_in[11];
    const float* ffW2  = (const float*)d_in[12];
    const float* ffb2  = (const float*)d_in[13];
    const float* eW1   = (const float*)d_in[14];
    const float* eb1   = (const float*)d_in[15];
    const float* eg    = (const float*)d_in[16];
    const float* ebt   = (const float*)d_in[17];
    const float* eW2   = (const float*)d_in[18];
    const float* eb2   = (const float*)d_in[19];
    const float* eW3   = (const float*)d_in[20];
    const float* eb3   = (const float*)d_in[21];
    const float* eW4   = (const float*)d_in[22];
    const float* aW1   = (const float*)d_in[23];
    const float* ab1   = (const float*)d_in[24];
    const float* ag    = (const float*)d_in[25];
    const float* abt   = (const float*)d_in[26];
    const float* aW2   = (const float*)d_in[27];
    const float* ab2   = (const float*)d_in[28];
    const float* aW3   = (const float*)d_in[29];
    const float* ab3   = (const float*)d_in[30];
    const float* aW4   = (const float*)d_in[31];
    float* out = (float*)d_out;

    float* ws   = (float*)d_ws;
    float* h    = ws;                    // 4 Mi floats
    float* ao   = ws + 4194304;
    float* tmp  = ws + 8388608;
    float* x1   = ws + 12582912;
    float* ff1  = ws + 16777216;         // 16 Mi floats (dead after layer loop)
    float* zraw = ws + 33554432;         // 8192 floats

    build_h<<<16384, 256, 0, stream>>>(x, h);

    for (int l = 0; l < 6; ++l) {
        attn_kernel<<<512, 256, 0, stream>>>(h, Wq + l * 1024, Wk + l * 1024,
                                             Wv + l * 1024, ao);
        gemm_mfma<<<dim3(2, 128), 256, 0, stream>>>(ao, Wo + l * 65536, bo + l * 256,
                                                    tmp, M_, 256, 256, 0);
        ln_residual<<<16384, 256, 0, stream>>>(tmp, h, ln1g + l * 256, ln1b + l * 256, x1);
        gemm_mfma<<<dim3(8, 128), 256, 0, stream>>>(x1, ffW1 + l * 262144, ffb1 + l * 1024,
                                                    ff1, M_, 1024, 256, 1);
        gemm_mfma<<<dim3(2, 128), 256, 0, stream>>>(ff1, ffW2 + l * 262144, ffb2 + l * 256,
                                                    tmp, M_, 256, 1024, 0);
        ln_residual<<<16384, 256, 0, stream>>>(tmp, x1, ln2g + l * 256, ln2b + l * 256, h);
    }

    // head: flat -> bf16 hi/lo (reuse ff1 region), then MFMA k-split GEMM
    u16* Bhi = (u16*)(ws + 16777216);             // 4 Mi u16 = 8 MB
    u16* Blo = (u16*)(ws + 16777216 + 2097152);   // 4 Mi u16 = 8 MB
    bsplit_kernel<<<4096, 256, 0, stream>>>(h, Bhi, Blo);
    zero_kernel<<<32, 256, 0, stream>>>(zraw);
    head_gemm<<<1024, 256, 0, stream>>>(eW1, aW1, Bhi, Blo, zraw);

    const float pi = 3.14159265358979323846f;
    mlp_head<<<16, 256, 0, stream>>>(zraw, eb1, eg, ebt, eW2, eb2, eW3, eb3, eW4,
                                     out, -pi / 4.f, pi / 2.f, 0);
    mlp_head<<<16, 256, 0, stream>>>(zraw + 4096, ab1, ag, abt, aW2, ab2, aW3, ab3, aW4,
                                     out, 0.f, 2.f * pi, 1);
}